// Round 1
// baseline (837.788 us; speedup 1.0000x reference)
//
#include <hip/hip_runtime.h>
#include <hip/hip_bf16.h>
#include <stdint.h>

#define DIM 384
#define QKVN 1152
#define NHEAD 12
#define HDIM 32
#define NTOK 49
#define NWIN 2048
static constexpr float SCALE_Q = 0.17677669529663687f;  // 32^-0.5

typedef float f32x4 __attribute__((ext_vector_type(4)));
typedef __bf16 bf16x8 __attribute__((ext_vector_type(8)));
typedef unsigned short u16;
typedef u16 u16x8 __attribute__((ext_vector_type(8)));
typedef u16 u16x4 __attribute__((ext_vector_type(4)));

static __device__ __forceinline__ u16 f2bf(float f) {
  __hip_bfloat16 h = __float2bfloat16(f);
  return __builtin_bit_cast(unsigned short, h);
}
static __device__ __forceinline__ f32x4 mfma_bf16(u16x8 a, u16x8 b, f32x4 c) {
  return __builtin_amdgcn_mfma_f32_16x16x32_bf16(
      __builtin_bit_cast(bf16x8, a), __builtin_bit_cast(bf16x8, b), c, 0, 0, 0);
}

// ---------------- fp32 -> bf16 convert (n % 4 == 0) ----------------
__global__ void k_convert(const float* __restrict__ s, u16* __restrict__ d, int n) {
  int i = (blockIdx.x * 256 + threadIdx.x) * 4;
  if (i < n) {
    float4 v = *(const float4*)(s + i);
    u16x4 o;
    o[0] = f2bf(v.x); o[1] = f2bf(v.y); o[2] = f2bf(v.z); o[3] = f2bf(v.w);
    *(u16x4*)(d + i) = o;
  }
}

// ---------------- pos-bias table: [12][49][49] fp32 ----------------
__global__ void k_posbias(const float* __restrict__ w1, const float* __restrict__ b1,
                          const float* __restrict__ w2, const float* __restrict__ b2,
                          float* __restrict__ out) {
  int idx = blockIdx.x * 256 + threadIdx.x;
  if (idx >= NTOK * NTOK) return;
  int i = idx / NTOK, j = idx % NTOK;
  float d0 = (float)(j / 7 - i / 7);
  float d1 = (float)(j % 7 - i % 7);
  d0 = copysignf(log1pf(fabsf(d0)), d0);
  d1 = copysignf(log1pf(fabsf(d1)), d1);
  float acc[NHEAD];
#pragma unroll
  for (int o2 = 0; o2 < NHEAD; o2++) acc[o2] = b2[o2];
#pragma unroll 4
  for (int o = 0; o < 32; o++) {
    float h = fmaxf(d0 * w1[o * 2] + d1 * w1[o * 2 + 1] + b1[o], 0.f);
#pragma unroll
    for (int o2 = 0; o2 < NHEAD; o2++) acc[o2] += h * w2[o2 * 32 + o];
  }
#pragma unroll
  for (int o2 = 0; o2 < NHEAD; o2++) out[(o2 * NTOK + i) * NTOK + j] = acc[o2];
}

// ---------------- GEMM: C = A @ W^T (+bias), 128x128 tile, BK=32 ----------------
// MODE 0: A = x fp32 (inline-convert), out = qkv bf16, cols<384 scaled by SCALE_Q
// MODE 1: A = attn_out bf16,           out = fp32 + proj_b
template <int MODE>
__global__ __launch_bounds__(256) void k_gemm(const void* __restrict__ Ap,
                                              const u16* __restrict__ Bw,
                                              const float* __restrict__ bias,
                                              void* __restrict__ Cp) {
  __shared__ u16 As[128 * 32];
  __shared__ u16 Bs[128 * 32];
  const int tid = threadIdx.x;
  const int bm = blockIdx.x, bn = blockIdx.y;
  const int lane = tid & 63, wv = tid >> 6;
  const int wr = wv >> 1, wc = wv & 1;           // 2x2 waves, 64x64 each
  const int l15 = lane & 15, l4 = lane >> 4;
  const int srow = tid >> 1, sseg = (tid & 1) * 16;
  f32x4 acc[4][4] = {};

  for (int k0 = 0; k0 < DIM; k0 += 32) {
    u16x8 aval0, aval1;
    if (MODE == 0) {
      const float* ap = (const float*)Ap + (size_t)(bm * 128 + srow) * DIM + k0 + sseg;
      float4 f0 = *(const float4*)(ap);
      float4 f1 = *(const float4*)(ap + 4);
      float4 f2 = *(const float4*)(ap + 8);
      float4 f3 = *(const float4*)(ap + 12);
      aval0[0] = f2bf(f0.x); aval0[1] = f2bf(f0.y); aval0[2] = f2bf(f0.z); aval0[3] = f2bf(f0.w);
      aval0[4] = f2bf(f1.x); aval0[5] = f2bf(f1.y); aval0[6] = f2bf(f1.z); aval0[7] = f2bf(f1.w);
      aval1[0] = f2bf(f2.x); aval1[1] = f2bf(f2.y); aval1[2] = f2bf(f2.z); aval1[3] = f2bf(f2.w);
      aval1[4] = f2bf(f3.x); aval1[5] = f2bf(f3.y); aval1[6] = f2bf(f3.z); aval1[7] = f2bf(f3.w);
    } else {
      const u16* ap = (const u16*)Ap + (size_t)(bm * 128 + srow) * DIM + k0 + sseg;
      aval0 = *(const u16x8*)ap;
      aval1 = *(const u16x8*)(ap + 8);
    }
    const u16* bp = Bw + (size_t)(bn * 128 + srow) * DIM + k0 + sseg;
    u16x8 bval0 = *(const u16x8*)bp;
    u16x8 bval1 = *(const u16x8*)(bp + 8);

    __syncthreads();   // previous iteration's fragment reads complete
    *(u16x8*)&As[srow * 32 + sseg] = aval0;
    *(u16x8*)&As[srow * 32 + sseg + 8] = aval1;
    *(u16x8*)&Bs[srow * 32 + sseg] = bval0;
    *(u16x8*)&Bs[srow * 32 + sseg + 8] = bval1;
    __syncthreads();

    u16x8 af[4], bfr[4];
#pragma unroll
    for (int m = 0; m < 4; m++)
      af[m] = *(const u16x8*)&As[(wr * 64 + m * 16 + l15) * 32 + l4 * 8];
#pragma unroll
    for (int n = 0; n < 4; n++)
      bfr[n] = *(const u16x8*)&Bs[(wc * 64 + n * 16 + l15) * 32 + l4 * 8];
#pragma unroll
    for (int m = 0; m < 4; m++)
#pragma unroll
      for (int n = 0; n < 4; n++)
        acc[m][n] = mfma_bf16(af[m], bfr[n], acc[m][n]);
  }

#pragma unroll
  for (int n = 0; n < 4; n++) {
    const int col = bn * 128 + wc * 64 + n * 16 + l15;
    const float bv = bias[col];
#pragma unroll
    for (int m = 0; m < 4; m++) {
      const int row0 = bm * 128 + wr * 64 + m * 16 + l4 * 4;
#pragma unroll
      for (int r = 0; r < 4; r++) {
        float v = acc[m][n][r] + bv;
        if (MODE == 0) {
          if (col < DIM) v *= SCALE_Q;
          ((u16*)Cp)[(size_t)(row0 + r) * QKVN + col] = f2bf(v);
        } else {
          ((float*)Cp)[(size_t)(row0 + r) * DIM + col] = v;
        }
      }
    }
  }
}

// ---------------- attention: 1 block = 1 window, 4 waves, loop 12 heads ----------------
__global__ __launch_bounds__(256) void k_attn(const u16* __restrict__ qkv,
                                              const float* __restrict__ posb,
                                              const float* __restrict__ mask,
                                              u16* __restrict__ aout) {
  __shared__ u16 qs[64 * 32];    // q rows (pad 49..63 zero)
  __shared__ u16 ks[64 * 32];    // k rows (pad zero)
  __shared__ u16 vts[32 * 72];   // v transposed [d][token], cols 49..71 zero
  __shared__ u16 ps[64 * 72];    // P bf16, row-major, +8 pad
  const int b = blockIdx.x;
  const int w = b & 63;          // mask window index = b % 64
  const int tid = threadIdx.x;
  const int lane = tid & 63, wv = tid >> 6;
  const int l15 = lane & 15, l4 = lane >> 4;

  for (int i = tid; i < 64 * 32; i += 256)
    if ((i >> 5) >= NTOK) { qs[i] = 0; ks[i] = 0; }
  for (int i = tid; i < 32 * 72; i += 256)
    if ((i % 72) >= NTOK) vts[i] = 0;

  for (int h = 0; h < NHEAD; ++h) {
    __syncthreads();   // previous head's MFMA reads complete before restage
    if (tid < 196) {
      const int row = tid >> 2, seg = (tid & 3) * 8;
      const u16* src = qkv + (size_t)(b * NTOK + row) * QKVN + h * HDIM + seg;
      *(u16x8*)&qs[row * 32 + seg] = *(const u16x8*)src;
      *(u16x8*)&ks[row * 32 + seg] = *(const u16x8*)(src + DIM);
    }
    for (int i = tid; i < NTOK * HDIM; i += 256) {
      const int n = i >> 5, d = i & 31;
      vts[d * 72 + n] = qkv[(size_t)(b * NTOK + n) * QKVN + 2 * DIM + h * HDIM + d];
    }
    __syncthreads();

    // S = q @ k^T : wave wv owns rows wv*16..wv*16+15
    u16x8 aq = *(const u16x8*)&qs[(wv * 16 + l15) * 32 + l4 * 8];
    f32x4 s[4];
#pragma unroll
    for (int n = 0; n < 4; n++) {
      u16x8 bk = *(const u16x8*)&ks[(n * 16 + l15) * 32 + l4 * 8];
      f32x4 z = {0.f, 0.f, 0.f, 0.f};
      s[n] = mfma_bf16(aq, bk, z);
    }

    // softmax over cols 0..48; lane holds rows wv*16 + l4*4 + r, cols n*16+l15
#pragma unroll
    for (int r = 0; r < 4; r++) {
      const int row = wv * 16 + l4 * 4 + r;
      const bool rok = row < NTOK;
      float sv[4];
#pragma unroll
      for (int n = 0; n < 4; n++) {
        const int col = n * 16 + l15;
        if (col < NTOK) {
          float add = 0.f;
          if (rok)
            add = posb[(h * NTOK + row) * NTOK + col] + mask[(w * NTOK + row) * NTOK + col];
          sv[n] = s[n][r] + add;
        } else {
          sv[n] = -1e30f;   // finite mask: no NaN on zero-padded rows
        }
      }
      float mx = fmaxf(fmaxf(sv[0], sv[1]), fmaxf(sv[2], sv[3]));
#pragma unroll
      for (int off = 1; off < 16; off <<= 1) mx = fmaxf(mx, __shfl_xor(mx, off));
      float e[4], sum = 0.f;
#pragma unroll
      for (int n = 0; n < 4; n++) {
        const int col = n * 16 + l15;
        e[n] = (col < NTOK) ? __expf(sv[n] - mx) : 0.f;
        sum += e[n];
      }
#pragma unroll
      for (int off = 1; off < 16; off <<= 1) sum += __shfl_xor(sum, off);
      const float inv = 1.0f / sum;
#pragma unroll
      for (int n = 0; n < 4; n++) ps[row * 72 + n * 16 + l15] = f2bf(e[n] * inv);
    }
    __syncthreads();   // all P rows visible

    // O = P @ V : wave wv owns rows wv*16..+15, K = 64 (2 steps), 32 cols (2 frags)
    f32x4 o[2] = {};
#pragma unroll
    for (int kk = 0; kk < 2; kk++) {
      u16x8 ap = *(const u16x8*)&ps[(wv * 16 + l15) * 72 + kk * 32 + l4 * 8];
#pragma unroll
      for (int n = 0; n < 2; n++) {
        u16x8 bvv = *(const u16x8*)&vts[(n * 16 + l15) * 72 + kk * 32 + l4 * 8];
        o[n] = mfma_bf16(ap, bvv, o[n]);
      }
    }
#pragma unroll
    for (int n = 0; n < 2; n++) {
      const int col = n * 16 + l15;
#pragma unroll
      for (int r = 0; r < 4; r++) {
        const int row = wv * 16 + l4 * 4 + r;
        if (row < NTOK)
          aout[(size_t)(b * NTOK + row) * DIM + h * HDIM + col] = f2bf(o[n][r]);
      }
    }
  }
}

// ---------------- launch ----------------
extern "C" void kernel_launch(void* const* d_in, const int* in_sizes, int n_in,
                              void* d_out, int out_size, void* d_ws, size_t ws_size,
                              hipStream_t stream) {
  const float* x      = (const float*)d_in[0];
  const float* mask   = (const float*)d_in[1];
  const float* qkv_w  = (const float*)d_in[2];
  const float* qkv_b  = (const float*)d_in[3];
  const float* proj_w = (const float*)d_in[4];
  const float* proj_b = (const float*)d_in[5];
  const float* pm_w1  = (const float*)d_in[6];
  const float* pm_b1  = (const float*)d_in[7];
  const float* pm_w2  = (const float*)d_in[8];
  const float* pm_b2  = (const float*)d_in[9];
  float* out = (float*)d_out;

  char* ws = (char*)d_ws;
  u16*   qkv   = (u16*)(ws + 0);            // 100352*1152*2 = 231,211,008
  u16*   wqkv  = (u16*)(ws + 231211008);    // 442368*2      =     884,736
  u16*   wproj = (u16*)(ws + 232095744);    // 147456*2      =     294,912
  float* posb  = (float*)(ws + 232390656);  // 12*49*49*4    =     115,248
  u16*   aout  = (u16*)(ws + 232505904);    // 100352*384*2  =  77,070,336
  // total ws need: 309,576,240 bytes

  k_convert<<<432, 256, 0, stream>>>(qkv_w, wqkv, 442368);
  k_convert<<<144, 256, 0, stream>>>(proj_w, wproj, 147456);
  k_posbias<<<10, 256, 0, stream>>>(pm_w1, pm_b1, pm_w2, pm_b2, posb);
  k_gemm<0><<<dim3(784, 9), 256, 0, stream>>>((const void*)x, wqkv, qkv_b, (void*)qkv);
  k_attn<<<2048, 256, 0, stream>>>(qkv, posb, mask, aout);
  k_gemm<1><<<dim3(784, 3), 256, 0, stream>>>((const void*)aout, wproj, proj_b, (void*)out);
}

// Round 2
// 687.405 us; speedup vs baseline: 1.2188x; 1.2188x over previous
//
#include <hip/hip_runtime.h>
#include <hip/hip_bf16.h>
#include <stdint.h>

#define DIM 384
#define QKVN 1152
#define NHEAD 12
#define HDIM 32
#define NTOK 49
#define NWIN 2048
static constexpr float SCALE_Q = 0.17677669529663687f;  // 32^-0.5

typedef float f32x4 __attribute__((ext_vector_type(4)));
typedef __bf16 bf16x8 __attribute__((ext_vector_type(8)));
typedef unsigned short u16;
typedef u16 u16x8 __attribute__((ext_vector_type(8)));
typedef u16 u16x4 __attribute__((ext_vector_type(4)));

static __device__ __forceinline__ u16 f2bf(float f) {
  __hip_bfloat16 h = __float2bfloat16(f);
  return __builtin_bit_cast(unsigned short, h);
}
static __device__ __forceinline__ f32x4 mfma_bf16(u16x8 a, u16x8 b, f32x4 c) {
  return __builtin_amdgcn_mfma_f32_16x16x32_bf16(
      __builtin_bit_cast(bf16x8, a), __builtin_bit_cast(bf16x8, b), c, 0, 0, 0);
}

// ---------------- fp32 -> bf16 convert (n % 4 == 0) ----------------
__global__ void k_convert(const float* __restrict__ s, u16* __restrict__ d, int n) {
  int i = (blockIdx.x * 256 + threadIdx.x) * 4;
  if (i < n) {
    float4 v = *(const float4*)(s + i);
    u16x4 o;
    o[0] = f2bf(v.x); o[1] = f2bf(v.y); o[2] = f2bf(v.z); o[3] = f2bf(v.w);
    *(u16x4*)(d + i) = o;
  }
}

// ---------------- pos-bias table: [12][49][49] fp32 ----------------
__global__ void k_posbias(const float* __restrict__ w1, const float* __restrict__ b1,
                          const float* __restrict__ w2, const float* __restrict__ b2,
                          float* __restrict__ out) {
  int idx = blockIdx.x * 256 + threadIdx.x;
  if (idx >= NTOK * NTOK) return;
  int i = idx / NTOK, j = idx % NTOK;
  float d0 = (float)(j / 7 - i / 7);
  float d1 = (float)(j % 7 - i % 7);
  d0 = copysignf(log1pf(fabsf(d0)), d0);
  d1 = copysignf(log1pf(fabsf(d1)), d1);
  float acc[NHEAD];
#pragma unroll
  for (int o2 = 0; o2 < NHEAD; o2++) acc[o2] = b2[o2];
#pragma unroll 4
  for (int o = 0; o < 32; o++) {
    float h = fmaxf(d0 * w1[o * 2] + d1 * w1[o * 2 + 1] + b1[o], 0.f);
#pragma unroll
    for (int o2 = 0; o2 < NHEAD; o2++) acc[o2] += h * w2[o2 * 32 + o];
  }
#pragma unroll
  for (int o2 = 0; o2 < NHEAD; o2++) out[(o2 * NTOK + i) * NTOK + j] = acc[o2];
}

// ---------------- fused posb+mask: pbm[w][h][49][49] ----------------
__global__ void k_pbm(const float* __restrict__ posb, const float* __restrict__ mask,
                      float* __restrict__ pbm) {
  int idx = blockIdx.x * 256 + threadIdx.x;
  if (idx >= 64 * NHEAD * NTOK * NTOK) return;
  int j = idx % (NTOK * NTOK);
  int t = idx / (NTOK * NTOK);
  int h = t % NHEAD, w = t / NHEAD;
  pbm[idx] = posb[h * NTOK * NTOK + j] + mask[w * NTOK * NTOK + j];
}

// ---------------- GEMM: C = A @ W^T (+bias), 128x128 tile, BK=32 ----------------
// LDS layout: row-major [128][32] u16, 16B-seg XOR-swizzled: seg' = seg ^ ((row>>1)&3)
// MODE 0: A = x fp32 (inline-convert), out = qkv bf16, cols<384 scaled by SCALE_Q
// MODE 1: A = attn_out bf16,           out = fp32 + proj_b
template <int MODE>
__global__ __launch_bounds__(256) void k_gemm(const void* __restrict__ Ap,
                                              const u16* __restrict__ Bw,
                                              const float* __restrict__ bias,
                                              void* __restrict__ Cp) {
  __shared__ u16 As[128 * 32];
  __shared__ u16 Bs[128 * 32];
  const int tid = threadIdx.x;
  // XCD-grouped, bn-fast flat order: 9 (or 3) blocks sharing one x-tile run
  // near-simultaneously on the same XCD -> x read ~once from HBM.
  const int NB = (MODE == 0) ? 9 : 3;
  const int PER = (MODE == 0) ? 882 : 294;  // gridDim.x / 8
  const int g = blockIdx.x;
  const int flat = (g & 7) * PER + (g >> 3);
  const int bm = flat / NB, bn = flat % NB;

  const int lane = tid & 63, wv = tid >> 6;
  const int wr = wv >> 1, wc = wv & 1;  // 2x2 waves, 64x64 each
  const int l15 = lane & 15, l4 = lane >> 4;
  const int srow = tid >> 1, sp = tid & 1;
  const int fS = (srow >> 1) & 3;
  const int ws0 = (2 * sp) ^ fS, ws1 = (2 * sp + 1) ^ fS;  // swizzled write segs
  const int fr = (l15 >> 1) & 3;                           // read-side swizzle
  f32x4 acc[4][4] = {};

  for (int k0 = 0; k0 < DIM; k0 += 32) {
    u16x8 aval0, aval1;
    if (MODE == 0) {
      const float* ap = (const float*)Ap + (size_t)(bm * 128 + srow) * DIM + k0 + sp * 16;
      float4 f0 = *(const float4*)(ap);
      float4 f1 = *(const float4*)(ap + 4);
      float4 f2 = *(const float4*)(ap + 8);
      float4 f3 = *(const float4*)(ap + 12);
      aval0[0] = f2bf(f0.x); aval0[1] = f2bf(f0.y); aval0[2] = f2bf(f0.z); aval0[3] = f2bf(f0.w);
      aval0[4] = f2bf(f1.x); aval0[5] = f2bf(f1.y); aval0[6] = f2bf(f1.z); aval0[7] = f2bf(f1.w);
      aval1[0] = f2bf(f2.x); aval1[1] = f2bf(f2.y); aval1[2] = f2bf(f2.z); aval1[3] = f2bf(f2.w);
      aval1[4] = f2bf(f3.x); aval1[5] = f2bf(f3.y); aval1[6] = f2bf(f3.z); aval1[7] = f2bf(f3.w);
    } else {
      const u16* ap = (const u16*)Ap + (size_t)(bm * 128 + srow) * DIM + k0 + sp * 16;
      aval0 = *(const u16x8*)ap;
      aval1 = *(const u16x8*)(ap + 8);
    }
    const u16* bp = Bw + (size_t)(bn * 128 + srow) * DIM + k0 + sp * 16;
    u16x8 bval0 = *(const u16x8*)bp;
    u16x8 bval1 = *(const u16x8*)(bp + 8);

    __syncthreads();  // previous iteration's fragment reads complete
    *(u16x8*)&As[srow * 32 + ws0 * 8] = aval0;
    *(u16x8*)&As[srow * 32 + ws1 * 8] = aval1;
    *(u16x8*)&Bs[srow * 32 + ws0 * 8] = bval0;
    *(u16x8*)&Bs[srow * 32 + ws1 * 8] = bval1;
    __syncthreads();

    u16x8 af[4], bfr[4];
#pragma unroll
    for (int m = 0; m < 4; m++)
      af[m] = *(const u16x8*)&As[(wr * 64 + m * 16 + l15) * 32 + (l4 ^ fr) * 8];
#pragma unroll
    for (int n = 0; n < 4; n++)
      bfr[n] = *(const u16x8*)&Bs[(wc * 64 + n * 16 + l15) * 32 + (l4 ^ fr) * 8];
#pragma unroll
    for (int m = 0; m < 4; m++)
#pragma unroll
      for (int n = 0; n < 4; n++)
        acc[m][n] = mfma_bf16(af[m], bfr[n], acc[m][n]);
  }

#pragma unroll
  for (int n = 0; n < 4; n++) {
    const int col = bn * 128 + wc * 64 + n * 16 + l15;
    const float bv = bias[col];
#pragma unroll
    for (int m = 0; m < 4; m++) {
      const int row0 = bm * 128 + wr * 64 + m * 16 + l4 * 4;
#pragma unroll
      for (int r = 0; r < 4; r++) {
        float v = acc[m][n][r] + bv;
        if (MODE == 0) {
          if (col < DIM) v *= SCALE_Q;
          ((u16*)Cp)[(size_t)(row0 + r) * QKVN + col] = f2bf(v);
        } else {
          ((float*)Cp)[(size_t)(row0 + r) * DIM + col] = v;
        }
      }
    }
  }
}

// ---------------- attention: 1 block = 1 window, 4 waves, pipelined 12-head loop ----------------
__global__ __launch_bounds__(256) void k_attn(const u16* __restrict__ qkv,
                                              const float* __restrict__ pbm,
                                              u16* __restrict__ aout) {
  __shared__ u16 qs[2][64 * 32];   // q rows (swizzled segs; rows 49..63 zero)
  __shared__ u16 ks[2][64 * 32];   // k rows (swizzled)
  __shared__ u16 vts[2][32 * 72];  // v transposed [d][token], tokens 49..71 zero
  __shared__ u16 ps[64 * 72];      // P bf16 (wave-private row blocks)
  // XCD-grouped window order: blocks on one XCD share 8 mask-window slices of pbm
  const int g = blockIdx.x;
  const int b = (((g >> 3) >> 3) << 6) + (g & 7) * 8 + ((g >> 3) & 7);
  const int w = b & 63;
  const int tid = threadIdx.x;
  const int lane = tid & 63, wv = tid >> 6;
  const int l15 = lane & 15, l4 = lane >> 4;
  const int fr = (l15 >> 1) & 3;

  for (int i = tid; i < 64 * 32; i += 256)
    if ((i >> 5) >= NTOK) { qs[0][i] = 0; qs[1][i] = 0; ks[0][i] = 0; ks[1][i] = 0; }
  for (int i = tid; i < 32 * 72; i += 256)
    if ((i % 72) >= NTOK) { vts[0][i] = 0; vts[1][i] = 0; }

  const int trow = tid >> 2, tseg = tid & 3;  // staging: q/k row=trow seg=tseg; v token=trow dseg=tseg
  const int fT = (trow >> 1) & 3;
  u16x8 rq, rk, rv;

#define LOAD_REGS(h)                                                              \
  if (tid < 196) {                                                                \
    const u16* src = qkv + (size_t)(b * NTOK + trow) * QKVN + (h) * HDIM + tseg * 8; \
    rq = *(const u16x8*)src;                                                      \
    rk = *(const u16x8*)(src + DIM);                                              \
    rv = *(const u16x8*)(src + 2 * DIM);                                          \
  }
#define WRITE_LDS(buf)                                                            \
  if (tid < 196) {                                                                \
    *(u16x8*)&qs[buf][trow * 32 + (tseg ^ fT) * 8] = rq;                          \
    *(u16x8*)&ks[buf][trow * 32 + (tseg ^ fT) * 8] = rk;                          \
    _Pragma("unroll") for (int j = 0; j < 8; j++)                                 \
        vts[buf][(tseg * 8 + j) * 72 + trow] = rv[j];                             \
  }

  LOAD_REGS(0)
  WRITE_LDS(0)

  for (int h = 0; h < NHEAD; ++h) {
    const int buf = h & 1;
    if (h + 1 < NHEAD) LOAD_REGS(h + 1)
    __syncthreads();  // buf's writes (from prev iter) visible; prev compute done

    // S = q @ k^T : wave wv owns rows wv*16..wv*16+15
    u16x8 aq = *(const u16x8*)&qs[buf][(wv * 16 + l15) * 32 + (l4 ^ fr) * 8];
    f32x4 s[4];
#pragma unroll
    for (int n = 0; n < 4; n++) {
      u16x8 bk = *(const u16x8*)&ks[buf][(n * 16 + l15) * 32 + (l4 ^ fr) * 8];
      f32x4 z = {0.f, 0.f, 0.f, 0.f};
      s[n] = mfma_bf16(aq, bk, z);
    }

    // softmax over cols 0..48; lane holds rows wv*16 + l4*4 + r, cols n*16+l15
    float inv[4];
#pragma unroll
    for (int r = 0; r < 4; r++) {
      const int row = wv * 16 + l4 * 4 + r;
      const bool rok = row < NTOK;
      const float* pr = pbm + ((size_t)(w * NHEAD + h) * NTOK + (rok ? row : 0)) * NTOK;
      float sv[4];
#pragma unroll
      for (int n = 0; n < 4; n++) {
        const int col = n * 16 + l15;
        sv[n] = (col < NTOK) ? s[n][r] + pr[col] : -1e30f;
      }
      float mx = fmaxf(fmaxf(sv[0], sv[1]), fmaxf(sv[2], sv[3]));
#pragma unroll
      for (int off = 1; off < 16; off <<= 1) mx = fmaxf(mx, __shfl_xor(mx, off));
      float e[4], sum = 0.f;
#pragma unroll
      for (int n = 0; n < 4; n++) {
        const int col = n * 16 + l15;
        e[n] = (col < NTOK) ? __expf(sv[n] - mx) : 0.f;
        sum += e[n];
      }
#pragma unroll
      for (int off = 1; off < 16; off <<= 1) sum += __shfl_xor(sum, off);
      inv[r] = 1.0f / sum;
#pragma unroll
      for (int n = 0; n < 4; n++) ps[row * 72 + n * 16 + l15] = f2bf(e[n]);
    }
    // ps rows are wave-private (wave wv writes & reads rows wv*16..+15): no barrier.

    // O = P @ V : K = 64 (2 steps), 32 cols (2 frags)
    f32x4 o[2] = {};
#pragma unroll
    for (int kk = 0; kk < 2; kk++) {
      u16x8 ap = *(const u16x8*)&ps[(wv * 16 + l15) * 72 + kk * 32 + l4 * 8];
#pragma unroll
      for (int n = 0; n < 2; n++) {
        u16x8 bvv = *(const u16x8*)&vts[buf][(n * 16 + l15) * 72 + kk * 32 + l4 * 8];
        o[n] = mfma_bf16(ap, bvv, o[n]);
      }
    }
#pragma unroll
    for (int n = 0; n < 2; n++) {
      const int col = n * 16 + l15;
#pragma unroll
      for (int r = 0; r < 4; r++) {
        const int row = wv * 16 + l4 * 4 + r;
        if (row < NTOK)
          aout[(size_t)(b * NTOK + row) * DIM + h * HDIM + col] = f2bf(o[n][r] * inv[r]);
      }
    }
    if (h + 1 < NHEAD) WRITE_LDS(buf ^ 1)  // disjoint from buf being read this iter
  }
#undef LOAD_REGS
#undef WRITE_LDS
}

// ---------------- launch ----------------
extern "C" void kernel_launch(void* const* d_in, const int* in_sizes, int n_in,
                              void* d_out, int out_size, void* d_ws, size_t ws_size,
                              hipStream_t stream) {
  const float* x      = (const float*)d_in[0];
  const float* mask   = (const float*)d_in[1];
  const float* qkv_w  = (const float*)d_in[2];
  const float* qkv_b  = (const float*)d_in[3];
  const float* proj_w = (const float*)d_in[4];
  const float* proj_b = (const float*)d_in[5];
  const float* pm_w1  = (const float*)d_in[6];
  const float* pm_b1  = (const float*)d_in[7];
  const float* pm_w2  = (const float*)d_in[8];
  const float* pm_b2  = (const float*)d_in[9];
  float* out = (float*)d_out;

  char* ws = (char*)d_ws;
  u16*   qkv   = (u16*)(ws + 0);            // 100352*1152*2 = 231,211,008
  u16*   wqkv  = (u16*)(ws + 231211008);    //                     884,736
  u16*   wproj = (u16*)(ws + 232095744);    //                     294,912
  float* posb  = (float*)(ws + 232390656);  // 12*49*49*4    =     115,248
  u16*   aout  = (u16*)(ws + 232505904);    // 100352*384*2  =  77,070,336
  float* pbm   = (float*)(ws + 309576240);  // 64*12*49*49*4 =   7,375,872
  // total ws need: 316,952,112 bytes

  k_convert<<<432, 256, 0, stream>>>(qkv_w, wqkv, 442368);
  k_convert<<<144, 256, 0, stream>>>(proj_w, wproj, 147456);
  k_posbias<<<10, 256, 0, stream>>>(pm_w1, pm_b1, pm_w2, pm_b2, posb);
  k_pbm<<<7203, 256, 0, stream>>>(posb, mask, pbm);
  k_gemm<0><<<7056, 256, 0, stream>>>((const void*)x, wqkv, qkv_b, (void*)qkv);
  k_attn<<<2048, 256, 0, stream>>>(qkv, pbm, aout);
  k_gemm<1><<<2352, 256, 0, stream>>>((const void*)aout, wproj, proj_b, (void*)out);
}

// Round 3
// 655.190 us; speedup vs baseline: 1.2787x; 1.0492x over previous
//
#include <hip/hip_runtime.h>
#include <hip/hip_bf16.h>
#include <stdint.h>

#define DIM 384
#define QKVN 1152
#define NHEAD 12
#define HDIM 32
#define NTOK 49
#define NWIN 2048
static constexpr float SCALE_Q = 0.17677669529663687f;  // 32^-0.5

typedef float f32x4 __attribute__((ext_vector_type(4)));
typedef float f32x4u __attribute__((ext_vector_type(4), aligned(4)));
typedef __bf16 bf16x8 __attribute__((ext_vector_type(8)));
typedef unsigned short u16;
typedef u16 u16x8 __attribute__((ext_vector_type(8)));
typedef u16 u16x4 __attribute__((ext_vector_type(4)));

static __device__ __forceinline__ u16 f2bf(float f) {
  __hip_bfloat16 h = __float2bfloat16(f);
  return __builtin_bit_cast(unsigned short, h);
}
static __device__ __forceinline__ f32x4 mfma_bf16(u16x8 a, u16x8 b, f32x4 c) {
  return __builtin_amdgcn_mfma_f32_16x16x32_bf16(
      __builtin_bit_cast(bf16x8, a), __builtin_bit_cast(bf16x8, b), c, 0, 0, 0);
}

// ---------------- fp32 -> bf16 convert (n % 4 == 0) ----------------
__global__ void k_convert(const float* __restrict__ s, u16* __restrict__ d, int n) {
  int i = (blockIdx.x * 256 + threadIdx.x) * 4;
  if (i < n) {
    f32x4 v = *(const f32x4*)(s + i);
    u16x4 o;
    o[0] = f2bf(v[0]); o[1] = f2bf(v[1]); o[2] = f2bf(v[2]); o[3] = f2bf(v[3]);
    *(u16x4*)(d + i) = o;
  }
}

// ---------------- pos-bias table: [12][49][49] fp32 ----------------
__global__ void k_posbias(const float* __restrict__ w1, const float* __restrict__ b1,
                          const float* __restrict__ w2, const float* __restrict__ b2,
                          float* __restrict__ out) {
  int idx = blockIdx.x * 256 + threadIdx.x;
  if (idx >= NTOK * NTOK) return;
  int i = idx / NTOK, j = idx % NTOK;
  float d0 = (float)(j / 7 - i / 7);
  float d1 = (float)(j % 7 - i % 7);
  d0 = copysignf(log1pf(fabsf(d0)), d0);
  d1 = copysignf(log1pf(fabsf(d1)), d1);
  float acc[NHEAD];
#pragma unroll
  for (int o2 = 0; o2 < NHEAD; o2++) acc[o2] = b2[o2];
#pragma unroll 4
  for (int o = 0; o < 32; o++) {
    float h = fmaxf(d0 * w1[o * 2] + d1 * w1[o * 2 + 1] + b1[o], 0.f);
#pragma unroll
    for (int o2 = 0; o2 < NHEAD; o2++) acc[o2] += h * w2[o2 * 32 + o];
  }
#pragma unroll
  for (int o2 = 0; o2 < NHEAD; o2++) out[(o2 * NTOK + i) * NTOK + j] = acc[o2];
}

// ---------------- fused posb+mask: pbm[w][h][49][49] ----------------
__global__ void k_pbm(const float* __restrict__ posb, const float* __restrict__ mask,
                      float* __restrict__ pbm) {
  int idx = blockIdx.x * 256 + threadIdx.x;
  if (idx >= 64 * NHEAD * NTOK * NTOK) return;
  int j = idx % (NTOK * NTOK);
  int t = idx / (NTOK * NTOK);
  int h = t % NHEAD, w = t / NHEAD;
  pbm[idx] = posb[h * NTOK * NTOK + j] + mask[w * NTOK * NTOK + j];
}

// ---------------- GEMM: C = A @ W^T (+bias), 128x128 tile, BK=32, pipelined ----------------
// LDS: row-major [128][32] u16, 16B-seg XOR-swizzled: seg' = seg ^ ((row>>1)&3)
// MODE 0: A = x fp32 (inline-convert), out = qkv bf16, cols<384 scaled by SCALE_Q
// MODE 1: A = attn_out bf16,           out = fp32 + proj_b
template <int MODE>
__global__ __launch_bounds__(256) void k_gemm(const void* __restrict__ Ap,
                                              const u16* __restrict__ Bw,
                                              const float* __restrict__ bias,
                                              void* __restrict__ Cp) {
  __shared__ u16 As[128 * 32];
  __shared__ u16 Bs[128 * 32];
  const int tid = threadIdx.x;
  // XCD-grouped, bn-fast flat order
  const int NB = (MODE == 0) ? 9 : 3;
  const int PER = (MODE == 0) ? 882 : 294;  // gridDim.x / 8
  const int g = blockIdx.x;
  const int flat = (g & 7) * PER + (g >> 3);
  const int bm = flat / NB, bn = flat % NB;

  const int lane = tid & 63, wv = tid >> 6;
  const int wr = wv >> 1, wc = wv & 1;  // 2x2 waves, 64x64 each
  const int l15 = lane & 15, l4 = lane >> 4;
  const int srow = tid >> 1, sp = tid & 1;
  const int fS = (srow >> 1) & 3;
  const int ws0 = (2 * sp) ^ fS, ws1 = (2 * sp + 1) ^ fS;  // swizzled write segs
  const int fr = (l15 >> 1) & 3;                           // read-side swizzle
  f32x4 acc[4][4] = {};

  // staging registers (raw): loads for iter k+1 are issued before the MFMAs of
  // iter k; the vmcnt wait (at the convert/copy below) lands AFTER those MFMAs.
  f32x4 fA0, fA1, fA2, fA3;
  u16x8 rA0, rA1, rB0, rB1;

#define GLOAD(K0)                                                                   \
  {                                                                                 \
    if (MODE == 0) {                                                                \
      const float* ap = (const float*)Ap + (size_t)(bm * 128 + srow) * DIM + (K0) + sp * 16; \
      fA0 = *(const f32x4*)(ap);                                                    \
      fA1 = *(const f32x4*)(ap + 4);                                                \
      fA2 = *(const f32x4*)(ap + 8);                                                \
      fA3 = *(const f32x4*)(ap + 12);                                               \
    } else {                                                                        \
      const u16* ap = (const u16*)Ap + (size_t)(bm * 128 + srow) * DIM + (K0) + sp * 16; \
      rA0 = *(const u16x8*)ap;                                                      \
      rA1 = *(const u16x8*)(ap + 8);                                                \
    }                                                                               \
    const u16* bp = Bw + (size_t)(bn * 128 + srow) * DIM + (K0) + sp * 16;          \
    rB0 = *(const u16x8*)bp;                                                        \
    rB1 = *(const u16x8*)(bp + 8);                                                  \
  }

  GLOAD(0)
  const int NK = DIM / 32;  // 12
  for (int it = 0; it < NK; ++it) {
    u16x8 wa0, wa1, wb0, wb1;
    if (MODE == 0) {
#pragma unroll
      for (int j = 0; j < 4; j++) {
        wa0[j] = f2bf(fA0[j]); wa0[j + 4] = f2bf(fA1[j]);
        wa1[j] = f2bf(fA2[j]); wa1[j + 4] = f2bf(fA3[j]);
      }
    } else {
      wa0 = rA0; wa1 = rA1;
    }
    wb0 = rB0; wb1 = rB1;

    __syncthreads();  // previous iteration's fragment reads complete
    *(u16x8*)&As[srow * 32 + ws0 * 8] = wa0;
    *(u16x8*)&As[srow * 32 + ws1 * 8] = wa1;
    *(u16x8*)&Bs[srow * 32 + ws0 * 8] = wb0;
    *(u16x8*)&Bs[srow * 32 + ws1 * 8] = wb1;
    __syncthreads();

    if (it + 1 < NK) GLOAD((it + 1) * 32)  // issue next-tile loads BEFORE MFMAs

    u16x8 af[4], bfr[4];
#pragma unroll
    for (int m = 0; m < 4; m++)
      af[m] = *(const u16x8*)&As[(wr * 64 + m * 16 + l15) * 32 + (l4 ^ fr) * 8];
#pragma unroll
    for (int n = 0; n < 4; n++)
      bfr[n] = *(const u16x8*)&Bs[(wc * 64 + n * 16 + l15) * 32 + (l4 ^ fr) * 8];
#pragma unroll
    for (int m = 0; m < 4; m++)
#pragma unroll
      for (int n = 0; n < 4; n++)
        acc[m][n] = mfma_bf16(af[m], bfr[n], acc[m][n]);
  }
#undef GLOAD

#pragma unroll
  for (int n = 0; n < 4; n++) {
    const int col = bn * 128 + wc * 64 + n * 16 + l15;
    const float bv = bias[col];
#pragma unroll
    for (int m = 0; m < 4; m++) {
      const int row0 = bm * 128 + wr * 64 + m * 16 + l4 * 4;
#pragma unroll
      for (int r = 0; r < 4; r++) {
        float v = acc[m][n][r] + bv;
        if (MODE == 0) {
          if (col < DIM) v *= SCALE_Q;
          ((u16*)Cp)[(size_t)(row0 + r) * QKVN + col] = f2bf(v);
        } else {
          ((float*)Cp)[(size_t)(row0 + r) * DIM + col] = v;
        }
      }
    }
  }
}

// ---------------- attention: 1 block = 1 window, 4 waves, pipelined 12-head loop ----------------
// Swapped QK^T: S^T = mfma(K_frag, Q_frag) puts a full score row (one q) per lane:
// row-max/sum are in-register + 2 shfl_xor across the l4 group.
__global__ __launch_bounds__(256) void k_attn(const u16* __restrict__ qkv,
                                              const float* __restrict__ pbm,
                                              u16* __restrict__ aout) {
  __shared__ u16 qs[2][64 * 32];   // q rows (swizzled segs; rows 49..63 zero)
  __shared__ u16 ks[2][64 * 32];   // k rows (swizzled)
  __shared__ u16 vts[2][32 * 72];  // v transposed [d][token], tokens 49..71 zero
  __shared__ u16 ps[64 * 72];      // P bf16 (wave-private row blocks)
  const int g = blockIdx.x;
  const int b = (((g >> 3) >> 3) << 6) + (g & 7) * 8 + ((g >> 3) & 7);
  const int w = b & 63;
  const int tid = threadIdx.x;
  const int lane = tid & 63, wv = tid >> 6;
  const int l15 = lane & 15, l4 = lane >> 4;
  const int fr = (l15 >> 1) & 3;

  for (int i = tid; i < 64 * 32; i += 256)
    if ((i >> 5) >= NTOK) { qs[0][i] = 0; qs[1][i] = 0; ks[0][i] = 0; ks[1][i] = 0; }
  for (int i = tid; i < 32 * 72; i += 256)
    if ((i % 72) >= NTOK) { vts[0][i] = 0; vts[1][i] = 0; }

  const int trow = tid >> 2, tseg = tid & 3;
  const int fT = (trow >> 1) & 3;
  u16x8 rq, rk, rv;

#define LOAD_REGS(h)                                                                 \
  if (tid < 196) {                                                                   \
    const u16* src = qkv + (size_t)(b * NTOK + trow) * QKVN + (h) * HDIM + tseg * 8; \
    rq = *(const u16x8*)src;                                                         \
    rk = *(const u16x8*)(src + DIM);                                                 \
    rv = *(const u16x8*)(src + 2 * DIM);                                             \
  }
#define WRITE_LDS(buf)                                                               \
  if (tid < 196) {                                                                   \
    *(u16x8*)&qs[buf][trow * 32 + (tseg ^ fT) * 8] = rq;                             \
    *(u16x8*)&ks[buf][trow * 32 + (tseg ^ fT) * 8] = rk;                             \
    _Pragma("unroll") for (int j = 0; j < 8; j++)                                    \
        vts[buf][(tseg * 8 + j) * 72 + trow] = rv[j];                                \
  }

  LOAD_REGS(0)
  WRITE_LDS(0)

  const int qrow = wv * 16 + l15;  // this lane's q-row in softmax phase
  const int qc = (qrow < NTOK) ? qrow : NTOK - 1;

  for (int h = 0; h < NHEAD; ++h) {
    const int buf = h & 1;
    if (h + 1 < NHEAD) LOAD_REGS(h + 1)
    __syncthreads();  // buf's writes (from prev iter) visible; prev compute done

    // S^T = K @ Q^T : wave wv owns q-cols (rows of S) wv*16..+15
    u16x8 bq = *(const u16x8*)&qs[buf][(wv * 16 + l15) * 32 + (l4 ^ fr) * 8];
    f32x4 s[4];
#pragma unroll
    for (int n = 0; n < 4; n++) {
      u16x8 ak = *(const u16x8*)&ks[buf][(n * 16 + l15) * 32 + (l4 ^ fr) * 8];
      f32x4 z = {0.f, 0.f, 0.f, 0.f};
      s[n] = mfma_bf16(ak, bq, z);  // lane: S[q=qrow][k = n*16 + l4*4 + r]
    }

    // softmax along k (fully in-lane + 2 shfls)
    const float* pr = pbm + ((size_t)(w * NHEAD + h) * NTOK + qc) * NTOK;
    float sv[4][4];
    float mx = -1e30f;
#pragma unroll
    for (int n = 0; n < 4; n++) {
      f32x4 p4 = *(const f32x4u*)(pr + n * 16 + l4 * 4);
#pragma unroll
      for (int r = 0; r < 4; r++) {
        const int k = n * 16 + l4 * 4 + r;
        float v = (k < NTOK) ? s[n][r] + p4[r] : -1e30f;
        sv[n][r] = v;
        mx = fmaxf(mx, v);
      }
    }
    mx = fmaxf(mx, __shfl_xor(mx, 16));
    mx = fmaxf(mx, __shfl_xor(mx, 32));
    float e[4][4], sum = 0.f;
#pragma unroll
    for (int n = 0; n < 4; n++)
#pragma unroll
      for (int r = 0; r < 4; r++) {
        const int k = n * 16 + l4 * 4 + r;
        e[n][r] = (k < NTOK) ? __expf(sv[n][r] - mx) : 0.f;
        sum += e[n][r];
      }
    sum += __shfl_xor(sum, 16);
    sum += __shfl_xor(sum, 32);
    const float inv = 1.0f / sum;
#pragma unroll
    for (int n = 0; n < 4; n++) {
      u16x4 pk;
#pragma unroll
      for (int r = 0; r < 4; r++) pk[r] = f2bf(e[n][r] * inv);
      *(u16x4*)&ps[qrow * 72 + n * 16 + l4 * 4] = pk;  // 8B packed write
    }
    // ps rows are wave-private: no barrier needed.

    // O = P @ V : K = 64 (2 steps), 32 cols (2 frags)
    f32x4 o[2] = {};
#pragma unroll
    for (int kk = 0; kk < 2; kk++) {
      u16x8 ap = *(const u16x8*)&ps[(wv * 16 + l15) * 72 + kk * 32 + l4 * 8];
#pragma unroll
      for (int n = 0; n < 2; n++) {
        u16x8 bvv = *(const u16x8*)&vts[buf][(n * 16 + l15) * 72 + kk * 32 + l4 * 8];
        o[n] = mfma_bf16(ap, bvv, o[n]);
      }
    }
#pragma unroll
    for (int n = 0; n < 2; n++) {
      const int col = n * 16 + l15;
#pragma unroll
      for (int r = 0; r < 4; r++) {
        const int row = wv * 16 + l4 * 4 + r;
        if (row < NTOK)
          aout[(size_t)(b * NTOK + row) * DIM + h * HDIM + col] = f2bf(o[n][r]);
      }
    }
    if (h + 1 < NHEAD) WRITE_LDS(buf ^ 1)  // disjoint from buf read this iter
  }
#undef LOAD_REGS
#undef WRITE_LDS
}

// ---------------- launch ----------------
extern "C" void kernel_launch(void* const* d_in, const int* in_sizes, int n_in,
                              void* d_out, int out_size, void* d_ws, size_t ws_size,
                              hipStream_t stream) {
  const float* x      = (const float*)d_in[0];
  const float* mask   = (const float*)d_in[1];
  const float* qkv_w  = (const float*)d_in[2];
  const float* qkv_b  = (const float*)d_in[3];
  const float* proj_w = (const float*)d_in[4];
  const float* proj_b = (const float*)d_in[5];
  const float* pm_w1  = (const float*)d_in[6];
  const float* pm_b1  = (const float*)d_in[7];
  const float* pm_w2  = (const float*)d_in[8];
  const float* pm_b2  = (const float*)d_in[9];
  float* out = (float*)d_out;

  char* ws = (char*)d_ws;
  u16*   qkv   = (u16*)(ws + 0);            // 100352*1152*2 = 231,211,008
  u16*   wqkv  = (u16*)(ws + 231211008);    //                     884,736
  u16*   wproj = (u16*)(ws + 232095744);    //                     294,912
  float* posb  = (float*)(ws + 232390656);  // 12*49*49*4    =     115,248
  float* pbm   = (float*)(ws + 232505904);  // 64*12*49*49*4 =   7,375,872  (OOB float4 tail lands in aout)
  u16*   aout  = (u16*)(ws + 239881776);    // 100352*384*2  =  77,070,336
  // total ws need: 316,952,112 bytes

  k_convert<<<432, 256, 0, stream>>>(qkv_w, wqkv, 442368);
  k_convert<<<144, 256, 0, stream>>>(proj_w, wproj, 147456);
  k_posbias<<<10, 256, 0, stream>>>(pm_w1, pm_b1, pm_w2, pm_b2, posb);
  k_pbm<<<7203, 256, 0, stream>>>(posb, mask, pbm);
  k_gemm<0><<<7056, 256, 0, stream>>>((const void*)x, wqkv, qkv_b, (void*)qkv);
  k_attn<<<2048, 256, 0, stream>>>(qkv, pbm, aout);
  k_gemm<1><<<2352, 256, 0, stream>>>((const void*)aout, wproj, proj_b, (void*)out);
}